// Round 2
// baseline (105.296 us; speedup 1.0000x reference)
//
#include <hip/hip_runtime.h>
#include <math.h>

#define NB 4
#define NN 512
#define ND 128
#define NC 10
#define TI 32
#define TJ 64
#define PAD 132  // stride 132 floats: rows at stride-16 differ by 4 banks -> worst 2-way (free)

__global__ __launch_bounds__(256, 2) void w2ner_main(
    const float* __restrict__ x, const int* __restrict__ span,
    const int* __restrict__ seqlen, const float* __restrict__ Wm,
    const float* __restrict__ bias, float* __restrict__ out,
    float* __restrict__ accum)
{
    __shared__ float sXi[TI * PAD];
    __shared__ float sXj[TJ * PAD];
    __shared__ float sW[NC * ND];   // transposed: sW[c*ND + d] = W[d*NC + c]
    __shared__ float sB[NC];
    __shared__ float sRed[4 * 5];

    const int tid = threadIdx.x;
    const int nti = NN / TI;                    // 16
    const int ntj = NN / TJ;                    // 8
    const int blk = blockIdx.x;
    const int b   = blk / (nti * ntj);
    const int rem = blk % (nti * ntj);
    const int i0  = (rem / ntj) * TI;
    const int j0  = (rem % ntj) * TJ;

    const float* xb = x + (size_t)b * NN * ND;

    // stage x tiles (coalesced float4): Xi 32 rows + Xj 64 rows = 3072 float4
    for (int idx = tid; idx < (TI + TJ) * (ND / 4); idx += 256) {
        int row = idx >> 5;            // 32 float4 per row
        int c4  = (idx & 31) << 2;
        if (row < TI) {
            float4 v = *reinterpret_cast<const float4*>(xb + (size_t)(i0 + row) * ND + c4);
            *reinterpret_cast<float4*>(sXi + row * PAD + c4) = v;
        } else {
            int r = row - TI;
            float4 v = *reinterpret_cast<const float4*>(xb + (size_t)(j0 + r) * ND + c4);
            *reinterpret_cast<float4*>(sXj + r * PAD + c4) = v;
        }
    }
    // stage W transposed [c][d]
    for (int idx = tid; idx < ND * NC; idx += 256) {
        int d = idx / NC, c = idx - d * NC;
        sW[c * ND + d] = Wm[idx];
    }
    if (tid < NC) sB[tid] = bias[tid];
    __syncthreads();

    const int ti = tid >> 4;   // 0..15 -> rows ti, ti+16         (p in 0..1)
    const int tj = tid & 15;   // 0..15 -> cols tj + 16*q, q=0..3 (q in 0..3)

    float acc[2][4][NC];
    #pragma unroll
    for (int p = 0; p < 2; ++p)
        #pragma unroll
        for (int q = 0; q < 4; ++q)
            #pragma unroll
            for (int c = 0; c < NC; ++c) acc[p][q][c] = 0.f;

    const float* pXi0 = sXi + ti * PAD;
    const float* pXi1 = sXi + (ti + 16) * PAD;
    const float* pXj  = sXj + tj * PAD;

    #pragma unroll 2
    for (int d4 = 0; d4 < ND; d4 += 4) {
        float4 af[2], bf[4];
        af[0] = *reinterpret_cast<const float4*>(pXi0 + d4);
        af[1] = *reinterpret_cast<const float4*>(pXi1 + d4);
        #pragma unroll
        for (int q = 0; q < 4; ++q)
            bf[q] = *reinterpret_cast<const float4*>(pXj + q * (16 * PAD) + d4);
        float4 w[NC];
        #pragma unroll
        for (int c = 0; c < NC; ++c)
            w[c] = *reinterpret_cast<const float4*>(sW + c * ND + d4);
        #pragma unroll
        for (int p = 0; p < 2; ++p) {
            #pragma unroll
            for (int q = 0; q < 4; ++q) {
                float4 pr;
                pr.x = af[p].x * bf[q].x;
                pr.y = af[p].y * bf[q].y;
                pr.z = af[p].z * bf[q].z;
                pr.w = af[p].w * bf[q].w;
                #pragma unroll
                for (int c = 0; c < NC; ++c) {
                    float a = acc[p][q][c];
                    a = fmaf(pr.x, w[c].x, a);
                    a = fmaf(pr.y, w[c].y, a);
                    a = fmaf(pr.z, w[c].z, a);
                    a = fmaf(pr.w, w[c].w, a);
                    acc[p][q][c] = a;
                }
            }
        }
    }

    const int sl = seqlen[b];
    float lsum = 0.f, accn = 0.f, tpn = 0.f, tnn = 0.f, fpn = 0.f;

    #pragma unroll
    for (int p = 0; p < 2; ++p) {
        #pragma unroll
        for (int q = 0; q < 4; ++q) {
            const int i = i0 + ti + p * 16;
            const int j = j0 + tj + q * 16;
            float l[NC];
            #pragma unroll
            for (int c = 0; c < NC; ++c) l[c] = acc[p][q][c] + sB[c];
            // first-occurrence argmax (matches jnp.argmax)
            int am = 0; float mx = l[0];
            #pragma unroll
            for (int c = 1; c < NC; ++c) { if (l[c] > mx) { mx = l[c]; am = c; } }
            float e[NC];
            float s = 0.f;
            #pragma unroll
            for (int c = 0; c < NC; ++c) { e[c] = __expf(l[c] - mx); s += e[c]; }
            const size_t off = (size_t)b * NN * NN + (size_t)i * NN + j;
            const int sp = span[off];
            // gather l[sp], e[sp] without runtime array index (avoid scratch)
            float lsp = l[0], esp = e[0];
            #pragma unroll
            for (int c = 1; c < NC; ++c) {
                lsp = (sp == c) ? l[c] : lsp;
                esp = (sp == c) ? e[c] : esp;
            }
            const float lp   = (lsp - mx) - __logf(s);  // log(prob)
            const float prob = esp / s;
            const float om   = 1.f - prob;
            const float lm   = -(om * om) * lp;         // focal loss term
            const bool v = (i < sl) && (j < sl);
            const int pred = v ? am : 0;
            out[off] = (float)pred;
            if (v) { lsum += lm; if (pred == sp) accn += 1.f; }
            if (sp > 0) { if (pred == sp) tpn += 1.f; else tnn += 1.f; }
            else if (pred > 0 && v) fpn += 1.f;
        }
    }

    // block reduction: 5 partials
    float vals[5] = { lsum, accn, tpn, tnn, fpn };
    #pragma unroll
    for (int k = 0; k < 5; ++k) {
        float vv = vals[k];
        for (int o = 32; o > 0; o >>= 1) vv += __shfl_down(vv, o);
        vals[k] = vv;
    }
    const int wave = tid >> 6;
    const int lane = tid & 63;
    if (lane == 0) {
        #pragma unroll
        for (int k = 0; k < 5; ++k) sRed[wave * 5 + k] = vals[k];
    }
    __syncthreads();
    if (tid < 5) {
        float t = sRed[tid] + sRed[5 + tid] + sRed[10 + tid] + sRed[15 + tid];
        atomicAdd(&accum[tid], t);
    }
}

__global__ void w2ner_final(const int* __restrict__ seqlen,
                            const float* __restrict__ accum,
                            float* __restrict__ out)
{
    if (threadIdx.x == 0 && blockIdx.x == 0) {
        float s2 = 0.f;
        for (int k = 0; k < NB; ++k) { float s = (float)seqlen[k]; s2 += s * s; }
        const size_t base = (size_t)NB * NN * NN;
        out[base + 0] = accum[2];            // tp
        out[base + 1] = accum[3];            // tn
        out[base + 2] = accum[4];            // fp
        out[base + 3] = accum[0] / s2;       // loss
        out[base + 4] = accum[1] / s2;       // accuracy
    }
}

extern "C" void kernel_launch(void* const* d_in, const int* in_sizes, int n_in,
                              void* d_out, int out_size, void* d_ws, size_t ws_size,
                              hipStream_t stream) {
    const float* x      = (const float*)d_in[0];
    const int*   span   = (const int*)d_in[1];
    const int*   seqlen = (const int*)d_in[2];
    const float* Wm     = (const float*)d_in[3];
    const float* bias   = (const float*)d_in[4];
    float* out   = (float*)d_out;
    float* accum = (float*)d_ws;

    hipMemsetAsync(accum, 0, 5 * sizeof(float), stream);
    const int nblk = NB * (NN / TI) * (NN / TJ);       // 512 blocks
    w2ner_main<<<dim3(nblk), 256, 0, stream>>>(x, span, seqlen, Wm, bias, out, accum);
    w2ner_final<<<1, 64, 0, stream>>>(seqlen, accum, out);
}

// Round 3
// 58.957 us; speedup vs baseline: 1.7860x; 1.7860x over previous
//
#include <hip/hip_runtime.h>
#include <math.h>

#define NB 4
#define NN 512
#define ND 128
#define NC 10
#define TILE 32
#define PAD 132  // row stride 132 floats: stride-16 rows differ by 4 banks -> worst 2-way (free)

__global__ __launch_bounds__(256) void w2ner_main(
    const float* __restrict__ x, const int* __restrict__ span,
    const int* __restrict__ seqlen, const float* __restrict__ Wm,
    const float* __restrict__ bias, float* __restrict__ out,
    float* __restrict__ accum)
{
    __shared__ float sXi[TILE * PAD];
    __shared__ float sXj[TILE * PAD];
    __shared__ float sW[NC * ND];   // transposed: sW[c*ND + d] = W[d*NC + c]
    __shared__ float sB[NC];
    __shared__ float sRed[4 * 5];

    const int tid = threadIdx.x;
    const int ntj = NN / TILE;                  // 16
    const int blk = blockIdx.x;
    const int b   = blk / (ntj * ntj);
    const int rem = blk % (ntj * ntj);
    const int i0  = (rem / ntj) * TILE;
    const int j0  = (rem % ntj) * TILE;

    const float* xb = x + (size_t)b * NN * ND;

    // stage x tiles (coalesced float4)
    for (int idx = tid; idx < TILE * (ND / 4); idx += 256) {
        int row = idx >> 5;            // 32 float4 per row
        int c4  = (idx & 31) << 2;
        float4 vi = *reinterpret_cast<const float4*>(xb + (size_t)(i0 + row) * ND + c4);
        float4 vj = *reinterpret_cast<const float4*>(xb + (size_t)(j0 + row) * ND + c4);
        *reinterpret_cast<float4*>(sXi + row * PAD + c4) = vi;
        *reinterpret_cast<float4*>(sXj + row * PAD + c4) = vj;
    }
    // stage W transposed [c][d]
    for (int idx = tid; idx < ND * NC; idx += 256) {
        int d = idx / NC, c = idx - d * NC;
        sW[c * ND + d] = Wm[idx];
    }
    if (tid < NC) sB[tid] = bias[tid];

    const int ti = tid >> 4;   // 0..15 -> rows ti, ti+16
    const int tj = tid & 15;   // 0..15 -> cols tj, tj+16

    // prefetch span for the 4 pairs this thread owns (hides under K-loop)
    size_t offs[2][2];
    int sp[2][2];
    #pragma unroll
    for (int p = 0; p < 2; ++p)
        #pragma unroll
        for (int q = 0; q < 2; ++q) {
            const int i = i0 + ti + p * 16;
            const int j = j0 + tj + q * 16;
            offs[p][q] = (size_t)b * NN * NN + (size_t)i * NN + j;
            sp[p][q]   = span[offs[p][q]];
        }
    const int sl = seqlen[b];

    __syncthreads();

    float acc[2][2][NC];
    #pragma unroll
    for (int p = 0; p < 2; ++p)
        #pragma unroll
        for (int q = 0; q < 2; ++q)
            #pragma unroll
            for (int c = 0; c < NC; ++c) acc[p][q][c] = 0.f;

    const float* pXi0 = sXi + ti * PAD;
    const float* pXi1 = sXi + (ti + 16) * PAD;
    const float* pXj0 = sXj + tj * PAD;
    const float* pXj1 = sXj + (tj + 16) * PAD;

    #pragma unroll 2
    for (int d4 = 0; d4 < ND; d4 += 4) {
        float4 af[2], bf[2];
        af[0] = *reinterpret_cast<const float4*>(pXi0 + d4);
        af[1] = *reinterpret_cast<const float4*>(pXi1 + d4);
        bf[0] = *reinterpret_cast<const float4*>(pXj0 + d4);
        bf[1] = *reinterpret_cast<const float4*>(pXj1 + d4);
        // pairwise products first (shared across the 10 classes)
        float4 pr[2][2];
        #pragma unroll
        for (int p = 0; p < 2; ++p)
            #pragma unroll
            for (int q = 0; q < 2; ++q) {
                pr[p][q].x = af[p].x * bf[q].x;
                pr[p][q].y = af[p].y * bf[q].y;
                pr[p][q].z = af[p].z * bf[q].z;
                pr[p][q].w = af[p].w * bf[q].w;
            }
        #pragma unroll
        for (int c = 0; c < NC; ++c) {
            float4 w = *reinterpret_cast<const float4*>(sW + c * ND + d4);
            #pragma unroll
            for (int p = 0; p < 2; ++p)
                #pragma unroll
                for (int q = 0; q < 2; ++q) {
                    float a = acc[p][q][c];
                    a = fmaf(pr[p][q].x, w.x, a);
                    a = fmaf(pr[p][q].y, w.y, a);
                    a = fmaf(pr[p][q].z, w.z, a);
                    a = fmaf(pr[p][q].w, w.w, a);
                    acc[p][q][c] = a;
                }
        }
    }

    float lsum = 0.f, accn = 0.f, tpn = 0.f, tnn = 0.f, fpn = 0.f;

    #pragma unroll
    for (int p = 0; p < 2; ++p) {
        #pragma unroll
        for (int q = 0; q < 2; ++q) {
            const int i = i0 + ti + p * 16;
            const int j = j0 + tj + q * 16;
            float l[NC];
            #pragma unroll
            for (int c = 0; c < NC; ++c) l[c] = acc[p][q][c] + sB[c];
            // first-occurrence argmax (matches jnp.argmax)
            int am = 0; float mx = l[0];
            #pragma unroll
            for (int c = 1; c < NC; ++c) { if (l[c] > mx) { mx = l[c]; am = c; } }
            float e[NC];
            float s = 0.f;
            #pragma unroll
            for (int c = 0; c < NC; ++c) { e[c] = __expf(l[c] - mx); s += e[c]; }
            const int spv = sp[p][q];
            // gather l[spv], e[spv] without runtime array index (avoid scratch)
            float lsp = l[0], esp = e[0];
            #pragma unroll
            for (int c = 1; c < NC; ++c) {
                lsp = (spv == c) ? l[c] : lsp;
                esp = (spv == c) ? e[c] : esp;
            }
            const float inv  = __builtin_amdgcn_rcpf(s);
            const float lp   = (lsp - mx) - __logf(s);  // log(prob)
            const float prob = esp * inv;
            const float om   = 1.f - prob;
            const float lm   = -(om * om) * lp;         // focal loss term
            const bool v = (i < sl) && (j < sl);
            const int pred = v ? am : 0;
            out[offs[p][q]] = (float)pred;
            if (v) { lsum += lm; if (pred == spv) accn += 1.f; }
            if (spv > 0) { if (pred == spv) tpn += 1.f; else tnn += 1.f; }
            else if (pred > 0 && v) fpn += 1.f;
        }
    }

    // block reduction: 5 partials
    float vals[5] = { lsum, accn, tpn, tnn, fpn };
    #pragma unroll
    for (int k = 0; k < 5; ++k) {
        float vv = vals[k];
        for (int o = 32; o > 0; o >>= 1) vv += __shfl_down(vv, o);
        vals[k] = vv;
    }
    const int wave = tid >> 6;
    const int lane = tid & 63;
    if (lane == 0) {
        #pragma unroll
        for (int k = 0; k < 5; ++k) sRed[wave * 5 + k] = vals[k];
    }
    __syncthreads();
    if (tid < 5) {
        float t = sRed[tid] + sRed[5 + tid] + sRed[10 + tid] + sRed[15 + tid];
        atomicAdd(&accum[tid], t);
    }
}

__global__ void w2ner_final(const int* __restrict__ seqlen,
                            const float* __restrict__ accum,
                            float* __restrict__ out)
{
    if (threadIdx.x == 0 && blockIdx.x == 0) {
        float s2 = 0.f;
        for (int k = 0; k < NB; ++k) { float s = (float)seqlen[k]; s2 += s * s; }
        const size_t base = (size_t)NB * NN * NN;
        out[base + 0] = accum[2];            // tp
        out[base + 1] = accum[3];            // tn
        out[base + 2] = accum[4];            // fp
        out[base + 3] = accum[0] / s2;       // loss
        out[base + 4] = accum[1] / s2;       // accuracy
    }
}

extern "C" void kernel_launch(void* const* d_in, const int* in_sizes, int n_in,
                              void* d_out, int out_size, void* d_ws, size_t ws_size,
                              hipStream_t stream) {
    const float* x      = (const float*)d_in[0];
    const int*   span   = (const int*)d_in[1];
    const int*   seqlen = (const int*)d_in[2];
    const float* Wm     = (const float*)d_in[3];
    const float* bias   = (const float*)d_in[4];
    float* out   = (float*)d_out;
    float* accum = (float*)d_ws;

    hipMemsetAsync(accum, 0, 5 * sizeof(float), stream);
    const int ntiles = NN / TILE;                      // 16
    dim3 grid(NB * ntiles * ntiles);                   // 1024 blocks
    w2ner_main<<<grid, 256, 0, stream>>>(x, span, seqlen, Wm, bias, out, accum);
    w2ner_final<<<1, 64, 0, stream>>>(seqlen, accum, out);
}

// Round 4
// 46.010 us; speedup vs baseline: 2.2886x; 1.2814x over previous
//
#include <hip/hip_runtime.h>
#include <math.h>

#define NB 4
#define NN 512
#define ND 128
#define NC 10
#define TILE 32
#define PAD 132  // row stride 132 floats: stride-16 rows differ by 4 banks -> worst 2-way (free)

typedef float f32x2 __attribute__((ext_vector_type(2)));

__global__ __launch_bounds__(256) void w2ner_main(
    const float* __restrict__ x, const int* __restrict__ span,
    const int* __restrict__ seqlen, const float* __restrict__ Wm,
    const float* __restrict__ bias, float* __restrict__ out,
    float* __restrict__ accum)
{
    __shared__ float sXi[TILE * PAD];
    __shared__ float sXj[TILE * PAD];
    __shared__ float sRed[4 * 5];

    const int tid = threadIdx.x;
    const int ntj = NN / TILE;                  // 16
    const int blk = blockIdx.x;
    const int b   = blk / (ntj * ntj);
    const int rem = blk % (ntj * ntj);
    const int i0  = (rem / ntj) * TILE;
    const int j0  = (rem % ntj) * TILE;

    const float* xb = x + (size_t)b * NN * ND;

    // stage x tiles (coalesced float4)
    for (int idx = tid; idx < TILE * (ND / 4); idx += 256) {
        int row = idx >> 5;            // 32 float4 per row
        int c4  = (idx & 31) << 2;
        float4 vi = *reinterpret_cast<const float4*>(xb + (size_t)(i0 + row) * ND + c4);
        float4 vj = *reinterpret_cast<const float4*>(xb + (size_t)(j0 + row) * ND + c4);
        *reinterpret_cast<float4*>(sXi + row * PAD + c4) = vi;
        *reinterpret_cast<float4*>(sXj + row * PAD + c4) = vj;
    }

    const int ti = tid >> 4;   // 0..15 -> rows ti, ti+16
    const int tj = tid & 15;   // 0..15 -> cols tj, tj+16

    // prefetch span for the 4 pairs this thread owns (hides under K-loop)
    size_t offs[2][2];
    int sp[2][2];
    #pragma unroll
    for (int p = 0; p < 2; ++p)
        #pragma unroll
        for (int q = 0; q < 2; ++q) {
            const int i = i0 + ti + p * 16;
            const int j = j0 + tj + q * 16;
            offs[p][q] = (size_t)b * NN * NN + (size_t)i * NN + j;
            sp[p][q]   = span[offs[p][q]];
        }
    const int sl = seqlen[b];

    __syncthreads();

    // acc2[p][q][k]: class pair (2k, 2k+1) accumulators
    f32x2 acc2[2][2][5];
    #pragma unroll
    for (int p = 0; p < 2; ++p)
        #pragma unroll
        for (int q = 0; q < 2; ++q)
            #pragma unroll
            for (int k = 0; k < 5; ++k) acc2[p][q][k] = (f32x2){0.f, 0.f};

    const float* pXi0 = sXi + ti * PAD;
    const float* pXi1 = sXi + (ti + 16) * PAD;
    const float* pXj0 = sXj + tj * PAD;
    const float* pXj1 = sXj + (tj + 16) * PAD;

    #pragma unroll 2
    for (int d4 = 0; d4 < ND; d4 += 4) {
        float4 af[2], bf[2];
        af[0] = *reinterpret_cast<const float4*>(pXi0 + d4);
        af[1] = *reinterpret_cast<const float4*>(pXi1 + d4);
        bf[0] = *reinterpret_cast<const float4*>(pXj0 + d4);
        bf[1] = *reinterpret_cast<const float4*>(pXj1 + d4);
        // pairwise products (4 per pair), shared across the 10 classes
        float prd[2][2][4];
        #pragma unroll
        for (int p = 0; p < 2; ++p)
            #pragma unroll
            for (int q = 0; q < 2; ++q) {
                prd[p][q][0] = af[p].x * bf[q].x;
                prd[p][q][1] = af[p].y * bf[q].y;
                prd[p][q][2] = af[p].z * bf[q].z;
                prd[p][q][3] = af[p].w * bf[q].w;
            }
        // W rows read with wave-uniform addresses -> scalar/L1 path, off the LDS pipe.
        // row d: 10 floats = 5 f32x2 (8B-aligned since d*10 dwords is even)
        #pragma unroll
        for (int dd = 0; dd < 4; ++dd) {
            const f32x2* Wrow = reinterpret_cast<const f32x2*>(Wm + (size_t)(d4 + dd) * NC);
            f32x2 w2[5];
            #pragma unroll
            for (int k = 0; k < 5; ++k) w2[k] = Wrow[k];
            #pragma unroll
            for (int p = 0; p < 2; ++p)
                #pragma unroll
                for (int q = 0; q < 2; ++q) {
                    const float pv = prd[p][q][dd];
                    const f32x2 pvv = (f32x2){pv, pv};
                    #pragma unroll
                    for (int k = 0; k < 5; ++k)
                        acc2[p][q][k] = __builtin_elementwise_fma(pvv, w2[k], acc2[p][q][k]);
                }
        }
    }

    float lsum = 0.f, accn = 0.f, tpn = 0.f, tnn = 0.f, fpn = 0.f;

    #pragma unroll
    for (int p = 0; p < 2; ++p) {
        #pragma unroll
        for (int q = 0; q < 2; ++q) {
            const int i = i0 + ti + p * 16;
            const int j = j0 + tj + q * 16;
            float l[NC];
            #pragma unroll
            for (int k = 0; k < 5; ++k) {
                l[2 * k]     = acc2[p][q][k].x + bias[2 * k];
                l[2 * k + 1] = acc2[p][q][k].y + bias[2 * k + 1];
            }
            // first-occurrence argmax (matches jnp.argmax)
            int am = 0; float mx = l[0];
            #pragma unroll
            for (int c = 1; c < NC; ++c) { if (l[c] > mx) { mx = l[c]; am = c; } }
            float e[NC];
            float s = 0.f;
            #pragma unroll
            for (int c = 0; c < NC; ++c) { e[c] = __expf(l[c] - mx); s += e[c]; }
            const int spv = sp[p][q];
            // gather l[spv], e[spv] without runtime array index (avoid scratch)
            float lsp = l[0], esp = e[0];
            #pragma unroll
            for (int c = 1; c < NC; ++c) {
                lsp = (spv == c) ? l[c] : lsp;
                esp = (spv == c) ? e[c] : esp;
            }
            const float inv  = __builtin_amdgcn_rcpf(s);
            const float lp   = (lsp - mx) - __logf(s);  // log(prob)
            const float prob = esp * inv;
            const float om   = 1.f - prob;
            const float lm   = -(om * om) * lp;         // focal loss term
            const bool v = (i < sl) && (j < sl);
            const int pred = v ? am : 0;
            out[offs[p][q]] = (float)pred;
            if (v) { lsum += lm; if (pred == spv) accn += 1.f; }
            if (spv > 0) { if (pred == spv) tpn += 1.f; else tnn += 1.f; }
            else if (pred > 0 && v) fpn += 1.f;
        }
    }

    // block reduction: 5 partials
    float vals[5] = { lsum, accn, tpn, tnn, fpn };
    #pragma unroll
    for (int k = 0; k < 5; ++k) {
        float vv = vals[k];
        for (int o = 32; o > 0; o >>= 1) vv += __shfl_down(vv, o);
        vals[k] = vv;
    }
    const int wave = tid >> 6;
    const int lane = tid & 63;
    if (lane == 0) {
        #pragma unroll
        for (int k = 0; k < 5; ++k) sRed[wave * 5 + k] = vals[k];
    }
    __syncthreads();
    if (tid < 5) {
        float t = sRed[tid] + sRed[5 + tid] + sRed[10 + tid] + sRed[15 + tid];
        atomicAdd(&accum[tid], t);
    }
}

__global__ void w2ner_final(const int* __restrict__ seqlen,
                            const float* __restrict__ accum,
                            float* __restrict__ out)
{
    if (threadIdx.x == 0 && blockIdx.x == 0) {
        float s2 = 0.f;
        for (int k = 0; k < NB; ++k) { float s = (float)seqlen[k]; s2 += s * s; }
        const size_t base = (size_t)NB * NN * NN;
        out[base + 0] = accum[2];            // tp
        out[base + 1] = accum[3];            // tn
        out[base + 2] = accum[4];            // fp
        out[base + 3] = accum[0] / s2;       // loss
        out[base + 4] = accum[1] / s2;       // accuracy
    }
}

extern "C" void kernel_launch(void* const* d_in, const int* in_sizes, int n_in,
                              void* d_out, int out_size, void* d_ws, size_t ws_size,
                              hipStream_t stream) {
    const float* x      = (const float*)d_in[0];
    const int*   span   = (const int*)d_in[1];
    const int*   seqlen = (const int*)d_in[2];
    const float* Wm     = (const float*)d_in[3];
    const float* bias   = (const float*)d_in[4];
    float* out   = (float*)d_out;
    float* accum = (float*)d_ws;

    hipMemsetAsync(accum, 0, 5 * sizeof(float), stream);
    const int ntiles = NN / TILE;                      // 16
    dim3 grid(NB * ntiles * ntiles);                   // 1024 blocks
    w2ner_main<<<grid, 256, 0, stream>>>(x, span, seqlen, Wm, bias, out, accum);
    w2ner_final<<<1, 64, 0, stream>>>(seqlen, accum, out);
}